// Round 7
// baseline (755.345 us; speedup 1.0000x reference)
//
#include <hip/hip_runtime.h>

#define HIDDEN 256
#define K_CODES 8192
#define N_TOK 32768           // 8 * 4096
#define ZST_ELEMS 8388608     // 8*4096*256
#define NBLK 64               // code-dim blocks in MFMA gemm (8192/128)
#define MARGIN 1.0e-3f        // >> worst-case split-bf16 score error ~1e-4
#define WL_CAP 65536

using short8 = __attribute__((ext_vector_type(8))) short;   // 8 bf16 (4 VGPRs)
using f32x4  = __attribute__((ext_vector_type(4))) float;   // MFMA C/D frag

// ---------- deterministic RNE fp32->bf16 ----------
__device__ __forceinline__ unsigned short f2bf(float f) {
    unsigned int u = __float_as_uint(f);
    return (unsigned short)((u + 0x7fffu + ((u >> 16) & 1u)) >> 16);
}
__device__ __forceinline__ float bf2f(unsigned short h) {
    return __uint_as_float(((unsigned int)h) << 16);
}

__device__ __forceinline__ void gl2lds16(const void* g, void* l) {
    __builtin_amdgcn_global_load_lds(
        (const __attribute__((address_space(1))) unsigned int*)g,
        (__attribute__((address_space(3))) unsigned int*)l, 16, 0, 0);
}

// orderable key: monotone float->uint, packed with code for lowest-idx tie-break
__device__ __forceinline__ unsigned long long score_key(float s, int code) {
    unsigned int u = __float_as_uint(s);
    u = (u & 0x80000000u) ? ~u : (u | 0x80000000u);
    return (((unsigned long long)u) << 32) | (unsigned int)code;
}

// -------- numpy-pairwise row sum-of-squares, 16 threads/row ------------------
// Thread (h,j) owns numpy accumulator r_j of half h: r = sum_i fl(x[128h+8i+j]^2),
// i ascending (serial chain preserved). Combine tree uses xor-shuffles; IEEE add
// is commutative so r0+r1 == r1+r0 bitwise -> np-pairwise order preserved.
__global__ void np_norms_kernel(const float* __restrict__ x, float* __restrict__ out,
                                int nrows) {
#pragma clang fp contract(off)
    int gt  = blockIdx.x * 256 + threadIdx.x;
    int row = gt >> 4;
    int sub = gt & 15;                 // h = sub>>3, j = sub&7
    if (row >= nrows) return;
    const float* p = x + (size_t)row * HIDDEN + (sub >> 3) * 128 + (sub & 7);
    float v = p[0];
    float r = v * v;                   // base-case init r_j = x[j]^2
    #pragma unroll
    for (int i = 1; i < 16; ++i) { float w = p[8 * i]; r += w * w; }
    r += __shfl_xor(r, 1, 64);         // (r0+r1), (r2+r3), ...
    r += __shfl_xor(r, 2, 64);         // ((r0+r1)+(r2+r3)), ...
    r += __shfl_xor(r, 4, 64);         // full 128-block sum
    r += __shfl_xor(r, 8, 64);         // blk0 + blk1
    if (sub == 0) out[row] = r;
}

// ---------------- split fp32 -> (hi, lo) bf16 ----------------
__global__ void split_kernel(const float* __restrict__ x,
                             unsigned short* __restrict__ hi,
                             unsigned short* __restrict__ lo, int n4) {
    int i = blockIdx.x * 256 + threadIdx.x;
    if (i >= n4) return;
    float4 v = ((const float4*)x)[i];
    ushort4 h, l;
    h.x = f2bf(v.x); l.x = f2bf(v.x - bf2f(h.x));
    h.y = f2bf(v.y); l.y = f2bf(v.y - bf2f(h.y));
    h.z = f2bf(v.z); l.z = f2bf(v.z - bf2f(h.z));
    h.w = f2bf(v.w); l.w = f2bf(v.w - bf2f(h.w));
    ((ushort4*)hi)[i] = h;
    ((ushort4*)lo)[i] = l;
}

// ------- MFMA score GEMM: fused 3-product K-loop, 64x64 wave tiles ----------
// 128x128 block tile, BK=32, 4 waves in 2x2: per kt each wave does 16
// ds_read_b128 (192 cyc) vs 48 MFMA (233 cyc) -> MFMA is the long pole.
__global__ __launch_bounds__(256, 2) void mfma_score_kernel(
    const unsigned short* __restrict__ Ah, const unsigned short* __restrict__ Al,
    const unsigned short* __restrict__ Bh, const unsigned short* __restrict__ Bl,
    const float* __restrict__ ne,
    float* __restrict__ p1, float* __restrict__ p2, unsigned short* __restrict__ piu) {

    __shared__ unsigned short Ahs[128 * 32];
    __shared__ unsigned short Als[128 * 32];
    __shared__ unsigned short Bhs[128 * 32];
    __shared__ unsigned short Bls[128 * 32];
    __shared__ float ms1[2][128];
    __shared__ float ms2[2][128];
    __shared__ int   mi [2][128];

    const int tid  = threadIdx.x;
    const int wm   = tid >> 6;
    const int wave_m = wm & 1;          // row half 0/1
    const int wave_n = wm >> 1;         // col half 0/1
    const int lane = tid & 63;
    const int L    = lane & 15;
    const int q    = lane >> 4;
    const int m0   = blockIdx.x * 128;
    const int nb   = blockIdx.y;
    const int n0   = nb * 128;

    f32x4 acc[4][4] = {};

    const short8* A8h = (const short8*)Ahs;
    const short8* A8l = (const short8*)Als;
    const short8* B8h = (const short8*)Bhs;
    const short8* B8l = (const short8*)Bls;

    for (int kt = 0; kt < 8; ++kt) {
        const int k0 = kt * 32;
        __syncthreads();                     // previous tiles consumed
        #pragma unroll
        for (int r = 0; r < 2; ++r) {
            int u   = tid + 256 * r;
            int row = u >> 2;
            int p   = u & 3;
            int ch  = p ^ ((row >> 1) & 3);  // XOR swizzle
            size_t ga = (size_t)(m0 + row) * HIDDEN + k0 + ch * 8;
            size_t gb = (size_t)(n0 + row) * HIDDEN + k0 + ch * 8;
            gl2lds16(Ah + ga, &Ahs[u * 8]);
            gl2lds16(Al + ga, &Als[u * 8]);
            gl2lds16(Bh + gb, &Bhs[u * 8]);
            gl2lds16(Bl + gb, &Bls[u * 8]);
        }
        __syncthreads();                     // drains vmcnt -> LDS ready

        short8 ah[4], al[4];
        #pragma unroll
        for (int tm = 0; tm < 4; ++tm) {
            int m  = wave_m * 64 + tm * 16 + L;
            int fi = m * 4 + (q ^ ((m >> 1) & 3));
            ah[tm] = A8h[fi];
            al[tm] = A8l[fi];
        }
        #pragma unroll
        for (int tn = 0; tn < 4; ++tn) {
            int n  = wave_n * 64 + tn * 16 + L;
            int fi = n * 4 + (q ^ ((n >> 1) & 3));
            short8 bh = B8h[fi];
            short8 bl = B8l[fi];
            #pragma unroll
            for (int tm = 0; tm < 4; ++tm) {
                acc[tm][tn] = __builtin_amdgcn_mfma_f32_16x16x32_bf16(
                    ah[tm], bh, acc[tm][tn], 0, 0, 0);
                acc[tm][tn] = __builtin_amdgcn_mfma_f32_16x16x32_bf16(
                    al[tm], bh, acc[tm][tn], 0, 0, 0);
                acc[tm][tn] = __builtin_amdgcn_mfma_f32_16x16x32_bf16(
                    ah[tm], bl, acc[tm][tn], 0, 0, 0);
            }
        }
    }

    // per-wave top-2 over this wave's 64 codes, then cross-wave merge via LDS
    float nev[4];
    #pragma unroll
    for (int tn = 0; tn < 4; ++tn) nev[tn] = ne[n0 + wave_n * 64 + tn * 16 + L];

    #pragma unroll
    for (int tm = 0; tm < 4; ++tm) {
        #pragma unroll
        for (int reg = 0; reg < 4; ++reg) {
            float m1 = 3.4e38f, m2 = 3.4e38f;
            int bi = 0;
            #pragma unroll
            for (int tn = 0; tn < 4; ++tn) {
                float s = nev[tn] - 2.0f * acc[tm][tn][reg];
                int lo = wave_n * 64 + tn * 16 + L;     // local code 0..127
                if (s < m1)      { m2 = m1; m1 = s; bi = lo; }
                else if (s < m2) { m2 = s; }
            }
            #pragma unroll
            for (int off = 1; off < 16; off <<= 1) {
                float o1 = __shfl_xor(m1, off, 64);
                float o2 = __shfl_xor(m2, off, 64);
                int   oi = __shfl_xor(bi, off, 64);
                if (o1 < m1 || (o1 == m1 && oi < bi)) {
                    m2 = fminf(m1, o2); m1 = o1; bi = oi;
                } else {
                    m2 = fminf(m2, o1);
                }
            }
            if (L == 0) {
                int row128 = wave_m * 64 + tm * 16 + q * 4 + reg;
                ms1[wave_n][row128] = m1;
                ms2[wave_n][row128] = m2;
                mi [wave_n][row128] = bi;
            }
        }
    }
    __syncthreads();
    if (tid < 128) {
        int row = tid;
        float a1 = ms1[0][row], a2 = ms2[0][row];
        int   ai = mi[0][row];
        float b1 = ms1[1][row], b2 = ms2[1][row];
        int   bi = mi[1][row];
        // half-0 codes < half-1 codes, so on tie keep half 0
        if (b1 < a1) { a2 = fminf(a1, b2); a1 = b1; ai = bi; }
        else         { a2 = fminf(a2, b1); }
        size_t mrow = (size_t)m0 + row;
        p1[(size_t)nb * N_TOK + mrow]  = a1;
        p2[(size_t)nb * N_TOK + mrow]  = a2;
        piu[(size_t)nb * N_TOK + mrow] = (unsigned short)ai;
    }
}

// ------- combine partials -> winner + ambiguity flag + pruned worklist ------
__global__ void combine_kernel(const float* __restrict__ p1, const float* __restrict__ p2,
                               const unsigned short* __restrict__ piu,
                               float* __restrict__ idxf, int* __restrict__ flags,
                               unsigned long long* __restrict__ slots,
                               int* __restrict__ wl, unsigned int* __restrict__ wcount) {
    int t = blockIdx.x * 256 + threadIdx.x;
    float m1 = 3.4e38f, m2 = 3.4e38f;
    int bi = 0;
    for (int nb = 0; nb < NBLK; ++nb) {       // ascending nb => ascending codes
        float o1 = p1[(size_t)nb * N_TOK + t];
        float o2 = p2[(size_t)nb * N_TOK + t];
        if (o1 < m1) {
            m2 = fminf(m1, o2); m1 = o1;
            bi = nb * 128 + (int)piu[(size_t)nb * N_TOK + t];
        } else {
            m2 = fminf(m2, o1);
        }
    }
    idxf[t]  = (float)bi;
    slots[t] = ~0ULL;
    bool amb = (m2 - m1 < MARGIN);
    flags[t] = amb ? 1 : 0;
    if (amb) {
        for (int nb = 0; nb < NBLK; ++nb) {
            if (p1[(size_t)nb * N_TOK + t] <= m1 + MARGIN) {
                unsigned int pos = atomicAdd(wcount, 1u);
                if (pos < WL_CAP) wl[pos] = (t << 6) | nb;
            }
        }
    }
}

// ---------------- rescue: np-exact rescan of pruned (token,chunk) items -----
__global__ __launch_bounds__(128) void rescue_scan(
    const float* __restrict__ z, const float* __restrict__ emb,
    const float* __restrict__ ne, const float* __restrict__ zn,
    const int* __restrict__ wl, const unsigned int* __restrict__ wcount,
    unsigned long long* __restrict__ slots) {
#pragma clang fp contract(off)
    __shared__ float zs[HIDDEN];
    __shared__ unsigned long long red[128];

    int nit = (int)*wcount;
    if (nit > WL_CAP) nit = WL_CAP;

    for (int item = blockIdx.x; item < nit; item += gridDim.x) {
        int w  = wl[item];
        int t  = w >> 6;
        int nb = w & 63;
        __syncthreads();                       // zs/red from previous item consumed
        if (threadIdx.x < 64)
            ((float4*)zs)[threadIdx.x] =
                ((const float4*)(z + (size_t)t * HIDDEN))[threadIdx.x];
        __syncthreads();

        int c = nb * 128 + threadIdx.x;        // one code per thread
        const float4* e4 = (const float4*)(emb + (size_t)c * HIDDEN);
        float acc = 0.0f;
        #pragma unroll 8
        for (int k4 = 0; k4 < 64; ++k4) {      // ascending-k single-acc FMA chain
            float4 ev = e4[k4];
            acc = __builtin_fmaf(ev.x, zs[k4 * 4 + 0], acc);
            acc = __builtin_fmaf(ev.y, zs[k4 * 4 + 1], acc);
            acc = __builtin_fmaf(ev.z, zs[k4 * 4 + 2], acc);
            acc = __builtin_fmaf(ev.w, zs[k4 * 4 + 3], acc);
        }
        float t1 = zn[t] - 2.0f * acc;         // np rounding order (R2-proven)
        float s  = t1 + ne[c];

        red[threadIdx.x] = score_key(s, c);
        __syncthreads();
        for (int off = 64; off; off >>= 1) {
            if (threadIdx.x < off) {
                unsigned long long o = red[threadIdx.x + off];
                if (o < red[threadIdx.x]) red[threadIdx.x] = o;
            }
            __syncthreads();
        }
        if (threadIdx.x == 0) atomicMin(&slots[t], red[0]);
    }
}

// ------- gather + straight-through + loss; folds rescue finalize ------------
__global__ void epilogue_kernel(const float* __restrict__ z, const float* __restrict__ emb,
                                const int* __restrict__ flags,
                                const unsigned long long* __restrict__ slots,
                                float* __restrict__ idxf, float* __restrict__ zst,
                                float* __restrict__ loss_accum) {
    int t4    = blockIdx.x * 256 + threadIdx.x;
    int token = t4 >> 6;
    int k4    = t4 & 63;

    int idx;
    if (flags[token]) idx = (int)(unsigned int)(slots[token] & 0xFFFFFFFFULL);
    else              idx = (int)idxf[token];
    if (k4 == 0) idxf[token] = (float)idx;     // all lanes read before this store

    float4 zv = ((const float4*)z)[t4];
    float4 ev = ((const float4*)emb)[(size_t)idx * 64 + k4];

    float dx = ev.x - zv.x, dy = ev.y - zv.y, dz = ev.z - zv.z, dw = ev.w - zv.w;
    float4 o = { zv.x + dx, zv.y + dy, zv.z + dz, zv.w + dw };
    ((float4*)zst)[t4] = o;

    float p = dx * dx + dy * dy + dz * dz + dw * dw;
    #pragma unroll
    for (int off = 32; off; off >>= 1) p += __shfl_down(p, off, 64);

    __shared__ float wsum[4];
    int lane = threadIdx.x & 63, w = threadIdx.x >> 6;
    if (lane == 0) wsum[w] = p;
    __syncthreads();
    if (threadIdx.x == 0)
        atomicAdd(loss_accum, wsum[0] + wsum[1] + wsum[2] + wsum[3]);
}

__global__ void finalize_kernel(const float* __restrict__ loss_accum,
                                float* __restrict__ out_losses) {
    float m = loss_accum[0] * (1.0f / (float)ZST_ELEMS);
    out_losses[0] = m;
    out_losses[1] = m;
}

// ---------------- launch ----------------
extern "C" void kernel_launch(void* const* d_in, const int* in_sizes, int n_in,
                              void* d_out, int out_size, void* d_ws, size_t ws_size,
                              hipStream_t stream) {
    const float* z   = (const float*)d_in[0];   // [8,4096,256]
    const float* emb = (const float*)d_in[1];   // [8192,256]

    float* out    = (float*)d_out;
    float* zst    = out;                        // 8388608
    float* idxf   = out + ZST_ELEMS;            // 32768
    float* losses = out + ZST_ELEMS + N_TOK;    // 2

    char* w = (char*)d_ws;
    unsigned short* Ah = (unsigned short*)w;    w += (size_t)N_TOK  * HIDDEN * 2;
    unsigned short* Al = (unsigned short*)w;    w += (size_t)N_TOK  * HIDDEN * 2;
    unsigned short* Bh = (unsigned short*)w;    w += (size_t)K_CODES * HIDDEN * 2;
    unsigned short* Bl = (unsigned short*)w;    w += (size_t)K_CODES * HIDDEN * 2;
    float* p1 = (float*)w;                      w += (size_t)NBLK * N_TOK * 4;
    float* p2 = (float*)w;                      w += (size_t)NBLK * N_TOK * 4;
    unsigned short* piu = (unsigned short*)w;   w += (size_t)NBLK * N_TOK * 2;
    float* ne = (float*)w;                      w += K_CODES * 4;
    float* zn = (float*)w;                      w += N_TOK * 4;
    int*   flags = (int*)w;                     w += N_TOK * 4;
    unsigned long long* slots = (unsigned long long*)w;  w += N_TOK * 8;
    int*   wl = (int*)w;                        w += WL_CAP * 4;
    float* loss_accum = (float*)w;              w += 4;
    unsigned int* wcount = (unsigned int*)w;    // adjacent to loss_accum

    hipMemsetAsync(loss_accum, 0, 8, stream);   // zero loss + worklist counter
    np_norms_kernel<<<K_CODES * 16 / 256, 256, 0, stream>>>(emb, ne, K_CODES);
    np_norms_kernel<<<N_TOK * 16 / 256, 256, 0, stream>>>(z, zn, N_TOK);
    split_kernel<<<(ZST_ELEMS / 4) / 256, 256, 0, stream>>>(z, Ah, Al, ZST_ELEMS / 4);
    split_kernel<<<(K_CODES * HIDDEN / 4) / 256, 256, 0, stream>>>(emb, Bh, Bl,
                                                                   K_CODES * HIDDEN / 4);
    dim3 gg(N_TOK / 128, NBLK);
    mfma_score_kernel<<<gg, 256, 0, stream>>>(Ah, Al, Bh, Bl, ne, p1, p2, piu);
    combine_kernel<<<N_TOK / 256, 256, 0, stream>>>(p1, p2, piu, idxf, flags,
                                                    slots, wl, wcount);
    rescue_scan<<<1024, 128, 0, stream>>>(z, emb, ne, zn, wl, wcount, slots);
    epilogue_kernel<<<(ZST_ELEMS / 4) / 256, 256, 0, stream>>>(z, emb, flags, slots,
                                                               idxf, zst, loss_accum);
    finalize_kernel<<<1, 1, 0, stream>>>(loss_accum, losses);
}

// Round 8
// 681.481 us; speedup vs baseline: 1.1084x; 1.1084x over previous
//
#include <hip/hip_runtime.h>

#define HIDDEN 256
#define K_CODES 8192
#define N_TOK 32768           // 8 * 4096
#define ZST_ELEMS 8388608     // 8*4096*256
#define NBLK 64               // code-dim blocks in MFMA gemm (8192/128)
#define MARGIN 1.0e-3f        // >> worst-case split-bf16 score error ~1e-4
#define WL_CAP 65536

using short8 = __attribute__((ext_vector_type(8))) short;   // 8 bf16 (4 VGPRs)
using f32x4  = __attribute__((ext_vector_type(4))) float;   // MFMA C/D frag

// ---------- deterministic RNE fp32->bf16 ----------
__device__ __forceinline__ unsigned short f2bf(float f) {
    unsigned int u = __float_as_uint(f);
    return (unsigned short)((u + 0x7fffu + ((u >> 16) & 1u)) >> 16);
}
__device__ __forceinline__ float bf2f(unsigned short h) {
    return __uint_as_float(((unsigned int)h) << 16);
}

__device__ __forceinline__ void gl2lds16(const void* g, void* l) {
    __builtin_amdgcn_global_load_lds(
        (const __attribute__((address_space(1))) unsigned int*)g,
        (__attribute__((address_space(3))) unsigned int*)l, 16, 0, 0);
}

// orderable key: monotone float->uint, packed with code for lowest-idx tie-break
__device__ __forceinline__ unsigned long long score_key(float s, int code) {
    unsigned int u = __float_as_uint(s);
    u = (u & 0x80000000u) ? ~u : (u | 0x80000000u);
    return (((unsigned long long)u) << 32) | (unsigned int)code;
}

// -------- numpy-pairwise row sum-of-squares, 16 threads/row (R6-proven) -----
__global__ void np_norms_kernel(const float* __restrict__ x, float* __restrict__ out,
                                int nrows) {
#pragma clang fp contract(off)
    int gt  = blockIdx.x * 256 + threadIdx.x;
    int row = gt >> 4;
    int sub = gt & 15;                 // h = sub>>3, j = sub&7
    if (row >= nrows) return;
    const float* p = x + (size_t)row * HIDDEN + (sub >> 3) * 128 + (sub & 7);
    float v = p[0];
    float r = v * v;                   // base-case init r_j = x[j]^2
    #pragma unroll
    for (int i = 1; i < 16; ++i) { float w = p[8 * i]; r += w * w; }
    r += __shfl_xor(r, 1, 64);         // IEEE add commutative -> np order preserved
    r += __shfl_xor(r, 2, 64);
    r += __shfl_xor(r, 4, 64);
    r += __shfl_xor(r, 8, 64);
    if (sub == 0) out[row] = r;
}

// ---------------- split fp32 -> (hi, lo) bf16 ----------------
__global__ void split_kernel(const float* __restrict__ x,
                             unsigned short* __restrict__ hi,
                             unsigned short* __restrict__ lo, int n4) {
    int i = blockIdx.x * 256 + threadIdx.x;
    if (i >= n4) return;
    float4 v = ((const float4*)x)[i];
    ushort4 h, l;
    h.x = f2bf(v.x); l.x = f2bf(v.x - bf2f(h.x));
    h.y = f2bf(v.y); l.y = f2bf(v.y - bf2f(h.y));
    h.z = f2bf(v.z); l.z = f2bf(v.z - bf2f(h.z));
    h.w = f2bf(v.w); l.w = f2bf(v.w - bf2f(h.w));
    ((ushort4*)hi)[i] = h;
    ((ushort4*)lo)[i] = l;
}

// ------- MFMA score GEMM: fused 3-product K-loop, 32x128 wave tiles ---------
// R5-proven config (433 us, 951 TF): 60 VGPR + 64 AGPR = 124 -> 4 waves/SIMD.
// Per kt per wave: 20 ds_read_b128 vs 48 MFMA; transient b-frags keep VGPR low.
__global__ __launch_bounds__(256, 2) void mfma_score_kernel(
    const unsigned short* __restrict__ Ah, const unsigned short* __restrict__ Al,
    const unsigned short* __restrict__ Bh, const unsigned short* __restrict__ Bl,
    const float* __restrict__ ne,
    float* __restrict__ p1, float* __restrict__ p2, unsigned short* __restrict__ piu) {

    __shared__ unsigned short Ahs[128 * 32];
    __shared__ unsigned short Als[128 * 32];
    __shared__ unsigned short Bhs[128 * 32];
    __shared__ unsigned short Bls[128 * 32];

    const int tid  = threadIdx.x;
    const int wm   = tid >> 6;
    const int lane = tid & 63;
    const int L    = lane & 15;
    const int q    = lane >> 4;
    const int m0   = blockIdx.x * 128;
    const int nb   = blockIdx.y;
    const int n0   = nb * 128;

    f32x4 acc[2][8] = {};

    const short8* A8h = (const short8*)Ahs;
    const short8* A8l = (const short8*)Als;
    const short8* B8h = (const short8*)Bhs;
    const short8* B8l = (const short8*)Bls;

    for (int kt = 0; kt < 8; ++kt) {
        const int k0 = kt * 32;
        __syncthreads();                     // previous tiles consumed
        #pragma unroll
        for (int r = 0; r < 2; ++r) {
            int u   = tid + 256 * r;
            int row = u >> 2;
            int p   = u & 3;
            int ch  = p ^ ((row >> 1) & 3);  // XOR swizzle
            size_t ga = (size_t)(m0 + row) * HIDDEN + k0 + ch * 8;
            size_t gb = (size_t)(n0 + row) * HIDDEN + k0 + ch * 8;
            gl2lds16(Ah + ga, &Ahs[u * 8]);
            gl2lds16(Al + ga, &Als[u * 8]);
            gl2lds16(Bh + gb, &Bhs[u * 8]);
            gl2lds16(Bl + gb, &Bls[u * 8]);
        }
        __syncthreads();                     // drains vmcnt -> LDS ready

        short8 ah[2], al[2];
        #pragma unroll
        for (int tm = 0; tm < 2; ++tm) {
            int m  = wm * 32 + tm * 16 + L;
            int fi = m * 4 + (q ^ ((m >> 1) & 3));
            ah[tm] = A8h[fi];
            al[tm] = A8l[fi];
        }
        #pragma unroll
        for (int tn = 0; tn < 8; ++tn) {
            int n  = tn * 16 + L;
            int fi = n * 4 + (q ^ ((n >> 1) & 3));
            short8 bh = B8h[fi];
            short8 bl = B8l[fi];
            #pragma unroll
            for (int tm = 0; tm < 2; ++tm) {
                acc[tm][tn] = __builtin_amdgcn_mfma_f32_16x16x32_bf16(
                    ah[tm], bh, acc[tm][tn], 0, 0, 0);
                acc[tm][tn] = __builtin_amdgcn_mfma_f32_16x16x32_bf16(
                    al[tm], bh, acc[tm][tn], 0, 0, 0);
                acc[tm][tn] = __builtin_amdgcn_mfma_f32_16x16x32_bf16(
                    ah[tm], bl, acc[tm][tn], 0, 0, 0);
            }
        }
    }

    float nev[8];
    #pragma unroll
    for (int tn = 0; tn < 8; ++tn) nev[tn] = ne[n0 + tn * 16 + L];

    #pragma unroll
    for (int tm = 0; tm < 2; ++tm) {
        #pragma unroll
        for (int reg = 0; reg < 4; ++reg) {
            float m1 = 3.4e38f, m2 = 3.4e38f;
            int bi = 0;
            #pragma unroll
            for (int tn = 0; tn < 8; ++tn) {
                float s = nev[tn] - 2.0f * acc[tm][tn][reg];
                int lo = tn * 16 + L;               // local code 0..127
                if (s < m1)      { m2 = m1; m1 = s; bi = lo; }
                else if (s < m2) { m2 = s; }
            }
            #pragma unroll
            for (int off = 1; off < 16; off <<= 1) {
                float o1 = __shfl_xor(m1, off, 64);
                float o2 = __shfl_xor(m2, off, 64);
                int   oi = __shfl_xor(bi, off, 64);
                if (o1 < m1 || (o1 == m1 && oi < bi)) {
                    m2 = fminf(m1, o2); m1 = o1; bi = oi;
                } else {
                    m2 = fminf(m2, o1);
                }
            }
            if (L == 0) {
                size_t mrow = (size_t)m0 + wm * 32 + tm * 16 + q * 4 + reg;
                p1[(size_t)nb * N_TOK + mrow]  = m1;
                p2[(size_t)nb * N_TOK + mrow]  = m2;
                piu[(size_t)nb * N_TOK + mrow] = (unsigned short)bi;
            }
        }
    }
}

// ------- combine partials -> winner + ambiguity flag + pruned worklist ------
__global__ void combine_kernel(const float* __restrict__ p1, const float* __restrict__ p2,
                               const unsigned short* __restrict__ piu,
                               float* __restrict__ idxf, int* __restrict__ flags,
                               unsigned long long* __restrict__ slots,
                               int* __restrict__ wl, unsigned int* __restrict__ wcount) {
    int t = blockIdx.x * 256 + threadIdx.x;
    float m1 = 3.4e38f, m2 = 3.4e38f;
    int bi = 0;
    for (int nb = 0; nb < NBLK; ++nb) {       // ascending nb => ascending codes
        float o1 = p1[(size_t)nb * N_TOK + t];
        float o2 = p2[(size_t)nb * N_TOK + t];
        if (o1 < m1) {
            m2 = fminf(m1, o2); m1 = o1;
            bi = nb * 128 + (int)piu[(size_t)nb * N_TOK + t];
        } else {
            m2 = fminf(m2, o1);
        }
    }
    idxf[t]  = (float)bi;
    slots[t] = ~0ULL;
    bool amb = (m2 - m1 < MARGIN);
    flags[t] = amb ? 1 : 0;
    if (amb) {
        for (int nb = 0; nb < NBLK; ++nb) {
            if (p1[(size_t)nb * N_TOK + t] <= m1 + MARGIN) {
                unsigned int pos = atomicAdd(wcount, 1u);
                if (pos < WL_CAP) wl[pos] = (t << 6) | nb;
            }
        }
    }
}

// ---------------- rescue: np-exact rescan of pruned (token,chunk) items -----
__global__ __launch_bounds__(128) void rescue_scan(
    const float* __restrict__ z, const float* __restrict__ emb,
    const float* __restrict__ ne, const float* __restrict__ zn,
    const int* __restrict__ wl, const unsigned int* __restrict__ wcount,
    unsigned long long* __restrict__ slots) {
#pragma clang fp contract(off)
    __shared__ float zs[HIDDEN];
    __shared__ unsigned long long red[128];

    int nit = (int)*wcount;
    if (nit > WL_CAP) nit = WL_CAP;

    for (int item = blockIdx.x; item < nit; item += gridDim.x) {
        int w  = wl[item];
        int t  = w >> 6;
        int nb = w & 63;
        __syncthreads();                       // zs/red from previous item consumed
        if (threadIdx.x < 64)
            ((float4*)zs)[threadIdx.x] =
                ((const float4*)(z + (size_t)t * HIDDEN))[threadIdx.x];
        __syncthreads();

        int c = nb * 128 + threadIdx.x;        // one code per thread
        const float4* e4 = (const float4*)(emb + (size_t)c * HIDDEN);
        float acc = 0.0f;
        #pragma unroll 8
        for (int k4 = 0; k4 < 64; ++k4) {      // ascending-k single-acc FMA chain
            float4 ev = e4[k4];
            acc = __builtin_fmaf(ev.x, zs[k4 * 4 + 0], acc);
            acc = __builtin_fmaf(ev.y, zs[k4 * 4 + 1], acc);
            acc = __builtin_fmaf(ev.z, zs[k4 * 4 + 2], acc);
            acc = __builtin_fmaf(ev.w, zs[k4 * 4 + 3], acc);
        }
        float t1 = zn[t] - 2.0f * acc;         // np rounding order (R2-proven)
        float s  = t1 + ne[c];

        red[threadIdx.x] = score_key(s, c);
        __syncthreads();
        for (int off = 64; off; off >>= 1) {
            if (threadIdx.x < off) {
                unsigned long long o = red[threadIdx.x + off];
                if (o < red[threadIdx.x]) red[threadIdx.x] = o;
            }
            __syncthreads();
        }
        if (threadIdx.x == 0) atomicMin(&slots[t], red[0]);
    }
}

// ------- gather + straight-through + loss; folds rescue finalize ------------
__global__ void epilogue_kernel(const float* __restrict__ z, const float* __restrict__ emb,
                                const int* __restrict__ flags,
                                const unsigned long long* __restrict__ slots,
                                float* __restrict__ idxf, float* __restrict__ zst,
                                float* __restrict__ loss_accum) {
    int t4    = blockIdx.x * 256 + threadIdx.x;
    int token = t4 >> 6;
    int k4    = t4 & 63;

    int idx;
    if (flags[token]) idx = (int)(unsigned int)(slots[token] & 0xFFFFFFFFULL);
    else              idx = (int)idxf[token];
    if (k4 == 0) idxf[token] = (float)idx;     // all lanes read before this store

    float4 zv = ((const float4*)z)[t4];
    float4 ev = ((const float4*)emb)[(size_t)idx * 64 + k4];

    float dx = ev.x - zv.x, dy = ev.y - zv.y, dz = ev.z - zv.z, dw = ev.w - zv.w;
    float4 o = { zv.x + dx, zv.y + dy, zv.z + dz, zv.w + dw };
    ((float4*)zst)[t4] = o;

    float p = dx * dx + dy * dy + dz * dz + dw * dw;
    #pragma unroll
    for (int off = 32; off; off >>= 1) p += __shfl_down(p, off, 64);

    __shared__ float wsum[4];
    int lane = threadIdx.x & 63, w = threadIdx.x >> 6;
    if (lane == 0) wsum[w] = p;
    __syncthreads();
    if (threadIdx.x == 0)
        atomicAdd(loss_accum, wsum[0] + wsum[1] + wsum[2] + wsum[3]);
}

__global__ void finalize_kernel(const float* __restrict__ loss_accum,
                                float* __restrict__ out_losses) {
    float m = loss_accum[0] * (1.0f / (float)ZST_ELEMS);
    out_losses[0] = m;
    out_losses[1] = m;
}

// ---------------- launch ----------------
extern "C" void kernel_launch(void* const* d_in, const int* in_sizes, int n_in,
                              void* d_out, int out_size, void* d_ws, size_t ws_size,
                              hipStream_t stream) {
    const float* z   = (const float*)d_in[0];   // [8,4096,256]
    const float* emb = (const float*)d_in[1];   // [8192,256]

    float* out    = (float*)d_out;
    float* zst    = out;                        // 8388608
    float* idxf   = out + ZST_ELEMS;            // 32768
    float* losses = out + ZST_ELEMS + N_TOK;    // 2

    char* w = (char*)d_ws;
    unsigned short* Ah = (unsigned short*)w;    w += (size_t)N_TOK  * HIDDEN * 2;
    unsigned short* Al = (unsigned short*)w;    w += (size_t)N_TOK  * HIDDEN * 2;
    unsigned short* Bh = (unsigned short*)w;    w += (size_t)K_CODES * HIDDEN * 2;
    unsigned short* Bl = (unsigned short*)w;    w += (size_t)K_CODES * HIDDEN * 2;
    float* p1 = (float*)w;                      w += (size_t)NBLK * N_TOK * 4;
    float* p2 = (float*)w;                      w += (size_t)NBLK * N_TOK * 4;
    unsigned short* piu = (unsigned short*)w;   w += (size_t)NBLK * N_TOK * 2;
    float* ne = (float*)w;                      w += K_CODES * 4;
    float* zn = (float*)w;                      w += N_TOK * 4;
    int*   flags = (int*)w;                     w += N_TOK * 4;
    unsigned long long* slots = (unsigned long long*)w;  w += N_TOK * 8;
    int*   wl = (int*)w;                        w += WL_CAP * 4;
    float* loss_accum = (float*)w;              w += 4;
    unsigned int* wcount = (unsigned int*)w;    // adjacent to loss_accum

    hipMemsetAsync(loss_accum, 0, 8, stream);   // zero loss + worklist counter
    np_norms_kernel<<<K_CODES * 16 / 256, 256, 0, stream>>>(emb, ne, K_CODES);
    np_norms_kernel<<<N_TOK * 16 / 256, 256, 0, stream>>>(z, zn, N_TOK);
    split_kernel<<<(ZST_ELEMS / 4) / 256, 256, 0, stream>>>(z, Ah, Al, ZST_ELEMS / 4);
    split_kernel<<<(K_CODES * HIDDEN / 4) / 256, 256, 0, stream>>>(emb, Bh, Bl,
                                                                   K_CODES * HIDDEN / 4);
    dim3 gg(N_TOK / 128, NBLK);
    mfma_score_kernel<<<gg, 256, 0, stream>>>(Ah, Al, Bh, Bl, ne, p1, p2, piu);
    combine_kernel<<<N_TOK / 256, 256, 0, stream>>>(p1, p2, piu, idxf, flags,
                                                    slots, wl, wcount);
    rescue_scan<<<1024, 128, 0, stream>>>(z, emb, ne, zn, wl, wcount, slots);
    epilogue_kernel<<<(ZST_ELEMS / 4) / 256, 256, 0, stream>>>(z, emb, flags, slots,
                                                               idxf, zst, loss_accum);
    finalize_kernel<<<1, 1, 0, stream>>>(loss_accum, losses);
}

// Round 9
// 680.073 us; speedup vs baseline: 1.1107x; 1.0021x over previous
//
#include <hip/hip_runtime.h>

#define HIDDEN 256
#define K_CODES 8192
#define N_TOK 32768           // 8 * 4096
#define ZST_ELEMS 8388608     // 8*4096*256
#define NBLK 64               // code-dim blocks in MFMA gemm (8192/128)
#define MARGIN 1.2e-2f        // ~2x8sigma of dropped Ah*Bl term (std ~7e-4)
#define WL_CAP 131072

using short8 = __attribute__((ext_vector_type(8))) short;   // 8 bf16 (4 VGPRs)
using f32x4  = __attribute__((ext_vector_type(4))) float;   // MFMA C/D frag

// ---------- deterministic RNE fp32->bf16 ----------
__device__ __forceinline__ unsigned short f2bf(float f) {
    unsigned int u = __float_as_uint(f);
    return (unsigned short)((u + 0x7fffu + ((u >> 16) & 1u)) >> 16);
}
__device__ __forceinline__ float bf2f(unsigned short h) {
    return __uint_as_float(((unsigned int)h) << 16);
}

__device__ __forceinline__ void gl2lds16(const void* g, void* l) {
    __builtin_amdgcn_global_load_lds(
        (const __attribute__((address_space(1))) unsigned int*)g,
        (__attribute__((address_space(3))) unsigned int*)l, 16, 0, 0);
}

// orderable key: monotone float->uint, packed with code for lowest-idx tie-break
__device__ __forceinline__ unsigned long long score_key(float s, int code) {
    unsigned int u = __float_as_uint(s);
    u = (u & 0x80000000u) ? ~u : (u | 0x80000000u);
    return (((unsigned long long)u) << 32) | (unsigned int)code;
}

// -------- numpy-pairwise row sum-of-squares, 16 threads/row (R6-proven) -----
__global__ void np_norms_kernel(const float* __restrict__ x, float* __restrict__ out,
                                int nrows) {
#pragma clang fp contract(off)
    int gt  = blockIdx.x * 256 + threadIdx.x;
    int row = gt >> 4;
    int sub = gt & 15;                 // h = sub>>3, j = sub&7
    if (row >= nrows) return;
    const float* p = x + (size_t)row * HIDDEN + (sub >> 3) * 128 + (sub & 7);
    float v = p[0];
    float r = v * v;                   // base-case init r_j = x[j]^2
    #pragma unroll
    for (int i = 1; i < 16; ++i) { float w = p[8 * i]; r += w * w; }
    r += __shfl_xor(r, 1, 64);         // IEEE add commutative -> np order preserved
    r += __shfl_xor(r, 2, 64);
    r += __shfl_xor(r, 4, 64);
    r += __shfl_xor(r, 8, 64);
    if (sub == 0) out[row] = r;
}

// ---------------- split fp32 -> (hi, lo) bf16 ----------------
__global__ void split_kernel(const float* __restrict__ x,
                             unsigned short* __restrict__ hi,
                             unsigned short* __restrict__ lo, int n4) {
    int i = blockIdx.x * 256 + threadIdx.x;
    if (i >= n4) return;
    float4 v = ((const float4*)x)[i];
    ushort4 h, l;
    h.x = f2bf(v.x); l.x = f2bf(v.x - bf2f(h.x));
    h.y = f2bf(v.y); l.y = f2bf(v.y - bf2f(h.y));
    h.z = f2bf(v.z); l.z = f2bf(v.z - bf2f(h.z));
    h.w = f2bf(v.w); l.w = f2bf(v.w - bf2f(h.w));
    ((ushort4*)hi)[i] = h;
    ((ushort4*)lo)[i] = l;
}

// ---------------- split fp32 -> hi bf16 only (emb: Bl unused) ---------------
__global__ void split_hi_kernel(const float* __restrict__ x,
                                unsigned short* __restrict__ hi, int n4) {
    int i = blockIdx.x * 256 + threadIdx.x;
    if (i >= n4) return;
    float4 v = ((const float4*)x)[i];
    ushort4 h;
    h.x = f2bf(v.x); h.y = f2bf(v.y); h.z = f2bf(v.z); h.w = f2bf(v.w);
    ((ushort4*)hi)[i] = h;
}

// ------- MFMA score GEMM: 2-product K-loop (Ah·Bh + Al·Bh), 32x128 waves ----
// Dropped Ah·Bl (score err std ~7e-4 << MARGIN). Per kt per wave: 12
// ds_read_b128 (144 cyc) vs 32 MFMA (155 cyc); 3 tiles staged (24 KB LDS).
__global__ __launch_bounds__(256, 2) void mfma_score_kernel(
    const unsigned short* __restrict__ Ah, const unsigned short* __restrict__ Al,
    const unsigned short* __restrict__ Bh,
    const float* __restrict__ ne,
    float* __restrict__ p1, float* __restrict__ p2, unsigned short* __restrict__ piu) {

    __shared__ unsigned short Ahs[128 * 32];
    __shared__ unsigned short Als[128 * 32];
    __shared__ unsigned short Bhs[128 * 32];

    const int tid  = threadIdx.x;
    const int wm   = tid >> 6;
    const int lane = tid & 63;
    const int L    = lane & 15;
    const int q    = lane >> 4;
    const int m0   = blockIdx.x * 128;
    const int nb   = blockIdx.y;
    const int n0   = nb * 128;

    f32x4 acc[2][8] = {};

    const short8* A8h = (const short8*)Ahs;
    const short8* A8l = (const short8*)Als;
    const short8* B8h = (const short8*)Bhs;

    for (int kt = 0; kt < 8; ++kt) {
        const int k0 = kt * 32;
        __syncthreads();                     // previous tiles consumed
        #pragma unroll
        for (int r = 0; r < 2; ++r) {
            int u   = tid + 256 * r;
            int row = u >> 2;
            int p   = u & 3;
            int ch  = p ^ ((row >> 1) & 3);  // XOR swizzle
            size_t ga = (size_t)(m0 + row) * HIDDEN + k0 + ch * 8;
            size_t gb = (size_t)(n0 + row) * HIDDEN + k0 + ch * 8;
            gl2lds16(Ah + ga, &Ahs[u * 8]);
            gl2lds16(Al + ga, &Als[u * 8]);
            gl2lds16(Bh + gb, &Bhs[u * 8]);
        }
        __syncthreads();                     // drains vmcnt -> LDS ready

        short8 ah[2], al[2];
        #pragma unroll
        for (int tm = 0; tm < 2; ++tm) {
            int m  = wm * 32 + tm * 16 + L;
            int fi = m * 4 + (q ^ ((m >> 1) & 3));
            ah[tm] = A8h[fi];
            al[tm] = A8l[fi];
        }
        #pragma unroll
        for (int tn = 0; tn < 8; ++tn) {
            int n  = tn * 16 + L;
            int fi = n * 4 + (q ^ ((n >> 1) & 3));
            short8 bh = B8h[fi];
            #pragma unroll
            for (int tm = 0; tm < 2; ++tm) {
                acc[tm][tn] = __builtin_amdgcn_mfma_f32_16x16x32_bf16(
                    ah[tm], bh, acc[tm][tn], 0, 0, 0);
                acc[tm][tn] = __builtin_amdgcn_mfma_f32_16x16x32_bf16(
                    al[tm], bh, acc[tm][tn], 0, 0, 0);
            }
        }
    }

    float nev[8];
    #pragma unroll
    for (int tn = 0; tn < 8; ++tn) nev[tn] = ne[n0 + tn * 16 + L];

    #pragma unroll
    for (int tm = 0; tm < 2; ++tm) {
        #pragma unroll
        for (int reg = 0; reg < 4; ++reg) {
            float m1 = 3.4e38f, m2 = 3.4e38f;
            int bi = 0;
            #pragma unroll
            for (int tn = 0; tn < 8; ++tn) {
                float s = nev[tn] - 2.0f * acc[tm][tn][reg];
                int lo = tn * 16 + L;               // local code 0..127
                if (s < m1)      { m2 = m1; m1 = s; bi = lo; }
                else if (s < m2) { m2 = s; }
            }
            #pragma unroll
            for (int off = 1; off < 16; off <<= 1) {
                float o1 = __shfl_xor(m1, off, 64);
                float o2 = __shfl_xor(m2, off, 64);
                int   oi = __shfl_xor(bi, off, 64);
                if (o1 < m1 || (o1 == m1 && oi < bi)) {
                    m2 = fminf(m1, o2); m1 = o1; bi = oi;
                } else {
                    m2 = fminf(m2, o1);
                }
            }
            if (L == 0) {
                size_t mrow = (size_t)m0 + wm * 32 + tm * 16 + q * 4 + reg;
                p1[(size_t)nb * N_TOK + mrow]  = m1;
                p2[(size_t)nb * N_TOK + mrow]  = m2;
                piu[(size_t)nb * N_TOK + mrow] = (unsigned short)bi;
            }
        }
    }
}

// ------- combine partials -> winner + ambiguity flag + pruned worklist ------
__global__ void combine_kernel(const float* __restrict__ p1, const float* __restrict__ p2,
                               const unsigned short* __restrict__ piu,
                               float* __restrict__ idxf, int* __restrict__ flags,
                               unsigned long long* __restrict__ slots,
                               int* __restrict__ wl, unsigned int* __restrict__ wcount) {
    int t = blockIdx.x * 256 + threadIdx.x;
    float m1 = 3.4e38f, m2 = 3.4e38f;
    int bi = 0;
    for (int nb = 0; nb < NBLK; ++nb) {       // ascending nb => ascending codes
        float o1 = p1[(size_t)nb * N_TOK + t];
        float o2 = p2[(size_t)nb * N_TOK + t];
        if (o1 < m1) {
            m2 = fminf(m1, o2); m1 = o1;
            bi = nb * 128 + (int)piu[(size_t)nb * N_TOK + t];
        } else {
            m2 = fminf(m2, o1);
        }
    }
    idxf[t]  = (float)bi;
    slots[t] = ~0ULL;
    bool amb = (m2 - m1 < MARGIN);
    flags[t] = amb ? 1 : 0;
    if (amb) {
        for (int nb = 0; nb < NBLK; ++nb) {
            if (p1[(size_t)nb * N_TOK + t] <= m1 + MARGIN) {
                unsigned int pos = atomicAdd(wcount, 1u);
                if (pos < WL_CAP) wl[pos] = (t << 6) | nb;
            }
        }
    }
}

// ---------------- rescue: np-exact rescan of pruned (token,chunk) items -----
__global__ __launch_bounds__(128) void rescue_scan(
    const float* __restrict__ z, const float* __restrict__ emb,
    const float* __restrict__ ne, const float* __restrict__ zn,
    const int* __restrict__ wl, const unsigned int* __restrict__ wcount,
    unsigned long long* __restrict__ slots) {
#pragma clang fp contract(off)
    __shared__ float zs[HIDDEN];
    __shared__ unsigned long long red[128];

    int nit = (int)*wcount;
    if (nit > WL_CAP) nit = WL_CAP;

    for (int item = blockIdx.x; item < nit; item += gridDim.x) {
        int w  = wl[item];
        int t  = w >> 6;
        int nb = w & 63;
        __syncthreads();                       // zs/red from previous item consumed
        if (threadIdx.x < 64)
            ((float4*)zs)[threadIdx.x] =
                ((const float4*)(z + (size_t)t * HIDDEN))[threadIdx.x];
        __syncthreads();

        int c = nb * 128 + threadIdx.x;        // one code per thread
        const float4* e4 = (const float4*)(emb + (size_t)c * HIDDEN);
        float acc = 0.0f;
        #pragma unroll 8
        for (int k4 = 0; k4 < 64; ++k4) {      // ascending-k single-acc FMA chain
            float4 ev = e4[k4];
            acc = __builtin_fmaf(ev.x, zs[k4 * 4 + 0], acc);
            acc = __builtin_fmaf(ev.y, zs[k4 * 4 + 1], acc);
            acc = __builtin_fmaf(ev.z, zs[k4 * 4 + 2], acc);
            acc = __builtin_fmaf(ev.w, zs[k4 * 4 + 3], acc);
        }
        float t1 = zn[t] - 2.0f * acc;         // np rounding order (R2-proven)
        float s  = t1 + ne[c];

        red[threadIdx.x] = score_key(s, c);
        __syncthreads();
        for (int off = 64; off; off >>= 1) {
            if (threadIdx.x < off) {
                unsigned long long o = red[threadIdx.x + off];
                if (o < red[threadIdx.x]) red[threadIdx.x] = o;
            }
            __syncthreads();
        }
        if (threadIdx.x == 0) atomicMin(&slots[t], red[0]);
    }
}

// ------- gather + straight-through + loss; folds rescue finalize ------------
__global__ void epilogue_kernel(const float* __restrict__ z, const float* __restrict__ emb,
                                const int* __restrict__ flags,
                                const unsigned long long* __restrict__ slots,
                                float* __restrict__ idxf, float* __restrict__ zst,
                                float* __restrict__ loss_accum) {
    int t4    = blockIdx.x * 256 + threadIdx.x;
    int token = t4 >> 6;
    int k4    = t4 & 63;

    int idx;
    if (flags[token]) idx = (int)(unsigned int)(slots[token] & 0xFFFFFFFFULL);
    else              idx = (int)idxf[token];
    if (k4 == 0) idxf[token] = (float)idx;     // all lanes read before this store

    float4 zv = ((const float4*)z)[t4];
    float4 ev = ((const float4*)emb)[(size_t)idx * 64 + k4];

    float dx = ev.x - zv.x, dy = ev.y - zv.y, dz = ev.z - zv.z, dw = ev.w - zv.w;
    float4 o = { zv.x + dx, zv.y + dy, zv.z + dz, zv.w + dw };
    ((float4*)zst)[t4] = o;

    float p = dx * dx + dy * dy + dz * dz + dw * dw;
    #pragma unroll
    for (int off = 32; off; off >>= 1) p += __shfl_down(p, off, 64);

    __shared__ float wsum[4];
    int lane = threadIdx.x & 63, w = threadIdx.x >> 6;
    if (lane == 0) wsum[w] = p;
    __syncthreads();
    if (threadIdx.x == 0)
        atomicAdd(loss_accum, wsum[0] + wsum[1] + wsum[2] + wsum[3]);
}

__global__ void finalize_kernel(const float* __restrict__ loss_accum,
                                float* __restrict__ out_losses) {
    float m = loss_accum[0] * (1.0f / (float)ZST_ELEMS);
    out_losses[0] = m;
    out_losses[1] = m;
}

// ---------------- launch ----------------
extern "C" void kernel_launch(void* const* d_in, const int* in_sizes, int n_in,
                              void* d_out, int out_size, void* d_ws, size_t ws_size,
                              hipStream_t stream) {
    const float* z   = (const float*)d_in[0];   // [8,4096,256]
    const float* emb = (const float*)d_in[1];   // [8192,256]

    float* out    = (float*)d_out;
    float* zst    = out;                        // 8388608
    float* idxf   = out + ZST_ELEMS;            // 32768
    float* losses = out + ZST_ELEMS + N_TOK;    // 2

    char* w = (char*)d_ws;
    unsigned short* Ah = (unsigned short*)w;    w += (size_t)N_TOK  * HIDDEN * 2;
    unsigned short* Al = (unsigned short*)w;    w += (size_t)N_TOK  * HIDDEN * 2;
    unsigned short* Bh = (unsigned short*)w;    w += (size_t)K_CODES * HIDDEN * 2;
    float* p1 = (float*)w;                      w += (size_t)NBLK * N_TOK * 4;
    float* p2 = (float*)w;                      w += (size_t)NBLK * N_TOK * 4;
    unsigned short* piu = (unsigned short*)w;   w += (size_t)NBLK * N_TOK * 2;
    float* ne = (float*)w;                      w += K_CODES * 4;
    float* zn = (float*)w;                      w += N_TOK * 4;
    int*   flags = (int*)w;                     w += N_TOK * 4;
    unsigned long long* slots = (unsigned long long*)w;  w += N_TOK * 8;
    int*   wl = (int*)w;                        w += (size_t)WL_CAP * 4;
    float* loss_accum = (float*)w;              w += 4;
    unsigned int* wcount = (unsigned int*)w;    // adjacent to loss_accum

    hipMemsetAsync(loss_accum, 0, 8, stream);   // zero loss + worklist counter
    np_norms_kernel<<<K_CODES * 16 / 256, 256, 0, stream>>>(emb, ne, K_CODES);
    np_norms_kernel<<<N_TOK * 16 / 256, 256, 0, stream>>>(z, zn, N_TOK);
    split_kernel<<<(ZST_ELEMS / 4) / 256, 256, 0, stream>>>(z, Ah, Al, ZST_ELEMS / 4);
    split_hi_kernel<<<(K_CODES * HIDDEN / 4) / 256, 256, 0, stream>>>(emb, Bh,
                                                                      K_CODES * HIDDEN / 4);
    dim3 gg(N_TOK / 128, NBLK);
    mfma_score_kernel<<<gg, 256, 0, stream>>>(Ah, Al, Bh, ne, p1, p2, piu);
    combine_kernel<<<N_TOK / 256, 256, 0, stream>>>(p1, p2, piu, idxf, flags,
                                                    slots, wl, wcount);
    rescue_scan<<<1024, 128, 0, stream>>>(z, emb, ne, zn, wl, wcount, slots);
    epilogue_kernel<<<(ZST_ELEMS / 4) / 256, 256, 0, stream>>>(z, emb, flags, slots,
                                                               idxf, zst, loss_accum);
    finalize_kernel<<<1, 1, 0, stream>>>(loss_accum, losses);
}

// Round 10
// 610.659 us; speedup vs baseline: 1.2369x; 1.1137x over previous
//
#include <hip/hip_runtime.h>

#define HIDDEN 256
#define K_CODES 8192
#define N_TOK 32768           // 8 * 4096
#define ZST_ELEMS 8388608     // 8*4096*256
#define NBLK 64               // code-dim blocks in MFMA gemm (8192/128)
#define MARGIN 5.0e-3f        // ~8 sigma of dropped Ah*Bl term (rms ~6.4e-4)
#define WL_CAP 131072

using short8 = __attribute__((ext_vector_type(8))) short;   // 8 bf16 (4 VGPRs)
using f32x4  = __attribute__((ext_vector_type(4))) float;   // MFMA C/D frag

// ---------- deterministic RNE fp32->bf16 ----------
__device__ __forceinline__ unsigned short f2bf(float f) {
    unsigned int u = __float_as_uint(f);
    return (unsigned short)((u + 0x7fffu + ((u >> 16) & 1u)) >> 16);
}
__device__ __forceinline__ float bf2f(unsigned short h) {
    return __uint_as_float(((unsigned int)h) << 16);
}

__device__ __forceinline__ void gl2lds16(const void* g, void* l) {
    __builtin_amdgcn_global_load_lds(
        (const __attribute__((address_space(1))) unsigned int*)g,
        (__attribute__((address_space(3))) unsigned int*)l, 16, 0, 0);
}

// orderable key: monotone float->uint, packed with code for lowest-idx tie-break
__device__ __forceinline__ unsigned long long score_key(float s, int code) {
    unsigned int u = __float_as_uint(s);
    u = (u & 0x80000000u) ? ~u : (u | 0x80000000u);
    return (((unsigned long long)u) << 32) | (unsigned int)code;
}

// -------- numpy-pairwise row sum-of-squares, 16 threads/row (R6-proven) -----
__global__ void np_norms_kernel(const float* __restrict__ x, float* __restrict__ out,
                                int nrows) {
#pragma clang fp contract(off)
    int gt  = blockIdx.x * 256 + threadIdx.x;
    int row = gt >> 4;
    int sub = gt & 15;                 // h = sub>>3, j = sub&7
    if (row >= nrows) return;
    const float* p = x + (size_t)row * HIDDEN + (sub >> 3) * 128 + (sub & 7);
    float v = p[0];
    float r = v * v;                   // base-case init r_j = x[j]^2
    #pragma unroll
    for (int i = 1; i < 16; ++i) { float w = p[8 * i]; r += w * w; }
    r += __shfl_xor(r, 1, 64);         // IEEE add commutative -> np order preserved
    r += __shfl_xor(r, 2, 64);
    r += __shfl_xor(r, 4, 64);
    r += __shfl_xor(r, 8, 64);
    if (sub == 0) out[row] = r;
}

// ---------------- split fp32 -> (hi, lo) bf16 ----------------
__global__ void split_kernel(const float* __restrict__ x,
                             unsigned short* __restrict__ hi,
                             unsigned short* __restrict__ lo, int n4) {
    int i = blockIdx.x * 256 + threadIdx.x;
    if (i >= n4) return;
    float4 v = ((const float4*)x)[i];
    ushort4 h, l;
    h.x = f2bf(v.x); l.x = f2bf(v.x - bf2f(h.x));
    h.y = f2bf(v.y); l.y = f2bf(v.y - bf2f(h.y));
    h.z = f2bf(v.z); l.z = f2bf(v.z - bf2f(h.z));
    h.w = f2bf(v.w); l.w = f2bf(v.w - bf2f(h.w));
    ((ushort4*)hi)[i] = h;
    ((ushort4*)lo)[i] = l;
}

// ---------------- split fp32 -> hi bf16 only (emb: Bl unused) ---------------
__global__ void split_hi_kernel(const float* __restrict__ x,
                                unsigned short* __restrict__ hi, int n4) {
    int i = blockIdx.x * 256 + threadIdx.x;
    if (i >= n4) return;
    float4 v = ((const float4*)x)[i];
    ushort4 h;
    h.x = f2bf(v.x); h.y = f2bf(v.y); h.z = f2bf(v.z); h.w = f2bf(v.w);
    ((ushort4*)hi)[i] = h;
}

// ------- MFMA score GEMM: 2-product K-loop (Ah·Bh + Al·Bh), 32x128 waves ----
// R8-proven: per kt per wave 12 ds_read_b128 vs 32 MFMA; 24 KB LDS; 60 VGPR.
__global__ __launch_bounds__(256, 2) void mfma_score_kernel(
    const unsigned short* __restrict__ Ah, const unsigned short* __restrict__ Al,
    const unsigned short* __restrict__ Bh,
    const float* __restrict__ ne,
    float* __restrict__ p1, float* __restrict__ p2, unsigned short* __restrict__ piu) {

    __shared__ unsigned short Ahs[128 * 32];
    __shared__ unsigned short Als[128 * 32];
    __shared__ unsigned short Bhs[128 * 32];

    const int tid  = threadIdx.x;
    const int wm   = tid >> 6;
    const int lane = tid & 63;
    const int L    = lane & 15;
    const int q    = lane >> 4;
    const int m0   = blockIdx.x * 128;
    const int nb   = blockIdx.y;
    const int n0   = nb * 128;

    f32x4 acc[2][8] = {};

    const short8* A8h = (const short8*)Ahs;
    const short8* A8l = (const short8*)Als;
    const short8* B8h = (const short8*)Bhs;

    for (int kt = 0; kt < 8; ++kt) {
        const int k0 = kt * 32;
        __syncthreads();                     // previous tiles consumed
        #pragma unroll
        for (int r = 0; r < 2; ++r) {
            int u   = tid + 256 * r;
            int row = u >> 2;
            int p   = u & 3;
            int ch  = p ^ ((row >> 1) & 3);  // XOR swizzle
            size_t ga = (size_t)(m0 + row) * HIDDEN + k0 + ch * 8;
            size_t gb = (size_t)(n0 + row) * HIDDEN + k0 + ch * 8;
            gl2lds16(Ah + ga, &Ahs[u * 8]);
            gl2lds16(Al + ga, &Als[u * 8]);
            gl2lds16(Bh + gb, &Bhs[u * 8]);
        }
        __syncthreads();                     // drains vmcnt -> LDS ready

        short8 ah[2], al[2];
        #pragma unroll
        for (int tm = 0; tm < 2; ++tm) {
            int m  = wm * 32 + tm * 16 + L;
            int fi = m * 4 + (q ^ ((m >> 1) & 3));
            ah[tm] = A8h[fi];
            al[tm] = A8l[fi];
        }
        #pragma unroll
        for (int tn = 0; tn < 8; ++tn) {
            int n  = tn * 16 + L;
            int fi = n * 4 + (q ^ ((n >> 1) & 3));
            short8 bh = B8h[fi];
            #pragma unroll
            for (int tm = 0; tm < 2; ++tm) {
                acc[tm][tn] = __builtin_amdgcn_mfma_f32_16x16x32_bf16(
                    ah[tm], bh, acc[tm][tn], 0, 0, 0);
                acc[tm][tn] = __builtin_amdgcn_mfma_f32_16x16x32_bf16(
                    al[tm], bh, acc[tm][tn], 0, 0, 0);
            }
        }
    }

    float nev[8];
    #pragma unroll
    for (int tn = 0; tn < 8; ++tn) nev[tn] = ne[n0 + tn * 16 + L];

    #pragma unroll
    for (int tm = 0; tm < 2; ++tm) {
        #pragma unroll
        for (int reg = 0; reg < 4; ++reg) {
            float m1 = 3.4e38f, m2 = 3.4e38f;
            int bi = 0;
            #pragma unroll
            for (int tn = 0; tn < 8; ++tn) {
                float s = nev[tn] - 2.0f * acc[tm][tn][reg];
                int lo = tn * 16 + L;               // local code 0..127
                if (s < m1)      { m2 = m1; m1 = s; bi = lo; }
                else if (s < m2) { m2 = s; }
            }
            #pragma unroll
            for (int off = 1; off < 16; off <<= 1) {
                float o1 = __shfl_xor(m1, off, 64);
                float o2 = __shfl_xor(m2, off, 64);
                int   oi = __shfl_xor(bi, off, 64);
                if (o1 < m1 || (o1 == m1 && oi < bi)) {
                    m2 = fminf(m1, o2); m1 = o1; bi = oi;
                } else {
                    m2 = fminf(m2, o1);
                }
            }
            if (L == 0) {
                size_t mrow = (size_t)m0 + wm * 32 + tm * 16 + q * 4 + reg;
                p1[(size_t)nb * N_TOK + mrow]  = m1;
                p2[(size_t)nb * N_TOK + mrow]  = m2;
                piu[(size_t)nb * N_TOK + mrow] = (unsigned short)bi;
            }
        }
    }
}

// ------- combine partials -> winner + ambiguity flag + pruned worklist ------
// Worklist items are (token, 64-code half-chunk): one wave each in rescue.
__global__ void combine_kernel(const float* __restrict__ p1, const float* __restrict__ p2,
                               const unsigned short* __restrict__ piu,
                               float* __restrict__ idxf, int* __restrict__ flags,
                               unsigned long long* __restrict__ slots,
                               int* __restrict__ wl, unsigned int* __restrict__ wcount) {
    int t = blockIdx.x * 256 + threadIdx.x;
    float m1 = 3.4e38f, m2 = 3.4e38f;
    int bi = 0;
    for (int nb = 0; nb < NBLK; ++nb) {       // ascending nb => ascending codes
        float o1 = p1[(size_t)nb * N_TOK + t];
        float o2 = p2[(size_t)nb * N_TOK + t];
        if (o1 < m1) {
            m2 = fminf(m1, o2); m1 = o1;
            bi = nb * 128 + (int)piu[(size_t)nb * N_TOK + t];
        } else {
            m2 = fminf(m2, o1);
        }
    }
    idxf[t]  = (float)bi;
    slots[t] = ~0ULL;
    bool amb = (m2 - m1 < MARGIN);
    flags[t] = amb ? 1 : 0;
    if (amb) {
        for (int nb = 0; nb < NBLK; ++nb) {
            if (p1[(size_t)nb * N_TOK + t] <= m1 + MARGIN) {
                unsigned int pos = atomicAdd(wcount, 2u);
                if (pos + 1 < WL_CAP) {
                    wl[pos]     = (t << 7) | (nb * 2);
                    wl[pos + 1] = (t << 7) | (nb * 2 + 1);
                }
            }
        }
    }
}

// ------ rescue: np-exact rescan, one wave per (token, 64-code) item ---------
__global__ __launch_bounds__(64) void rescue_scan(
    const float* __restrict__ z, const float* __restrict__ emb,
    const float* __restrict__ ne, const float* __restrict__ zn,
    const int* __restrict__ wl, const unsigned int* __restrict__ wcount,
    unsigned long long* __restrict__ slots) {
#pragma clang fp contract(off)
    __shared__ float zs[HIDDEN];

    int nit = (int)*wcount;
    if (nit > WL_CAP) nit = WL_CAP;

    for (int item = blockIdx.x; item < nit; item += gridDim.x) {
        int w   = wl[item];
        int t   = w >> 7;
        int nb2 = w & 127;                     // half-chunk: codes nb2*64..+63
        __syncthreads();                       // zs from previous item consumed
        ((float4*)zs)[threadIdx.x] = ((const float4*)(z + (size_t)t * HIDDEN))[threadIdx.x];
        __syncthreads();

        int c = nb2 * 64 + threadIdx.x;        // one code per lane
        const float4* e4 = (const float4*)(emb + (size_t)c * HIDDEN);
        float acc = 0.0f;
        #pragma unroll 8
        for (int k4 = 0; k4 < 64; ++k4) {      // ascending-k single-acc FMA chain
            float4 ev = e4[k4];
            acc = __builtin_fmaf(ev.x, zs[k4 * 4 + 0], acc);
            acc = __builtin_fmaf(ev.y, zs[k4 * 4 + 1], acc);
            acc = __builtin_fmaf(ev.z, zs[k4 * 4 + 2], acc);
            acc = __builtin_fmaf(ev.w, zs[k4 * 4 + 3], acc);
        }
        float t1 = zn[t] - 2.0f * acc;         // np rounding order (R2-proven)
        float s  = t1 + ne[c];

        unsigned long long key = score_key(s, c);
        #pragma unroll
        for (int off = 1; off < 64; off <<= 1) {
            unsigned long long o = __shfl_xor(key, off, 64);
            if (o < key) key = o;
        }
        if (threadIdx.x == 0) atomicMin(&slots[t], key);
    }
}

// ------- gather + straight-through + loss; folds rescue finalize ------------
__global__ void epilogue_kernel(const float* __restrict__ z, const float* __restrict__ emb,
                                const int* __restrict__ flags,
                                const unsigned long long* __restrict__ slots,
                                float* __restrict__ idxf, float* __restrict__ zst,
                                float* __restrict__ loss_accum) {
    int t4    = blockIdx.x * 256 + threadIdx.x;
    int token = t4 >> 6;
    int k4    = t4 & 63;

    int idx;
    if (flags[token]) idx = (int)(unsigned int)(slots[token] & 0xFFFFFFFFULL);
    else              idx = (int)idxf[token];
    if (k4 == 0) idxf[token] = (float)idx;     // all lanes read before this store

    float4 zv = ((const float4*)z)[t4];
    float4 ev = ((const float4*)emb)[(size_t)idx * 64 + k4];

    float dx = ev.x - zv.x, dy = ev.y - zv.y, dz = ev.z - zv.z, dw = ev.w - zv.w;
    float4 o = { zv.x + dx, zv.y + dy, zv.z + dz, zv.w + dw };
    ((float4*)zst)[t4] = o;

    float p = dx * dx + dy * dy + dz * dz + dw * dw;
    #pragma unroll
    for (int off = 32; off; off >>= 1) p += __shfl_down(p, off, 64);

    __shared__ float wsum[4];
    int lane = threadIdx.x & 63, w = threadIdx.x >> 6;
    if (lane == 0) wsum[w] = p;
    __syncthreads();
    if (threadIdx.x == 0)
        atomicAdd(loss_accum, wsum[0] + wsum[1] + wsum[2] + wsum[3]);
}

__global__ void finalize_kernel(const float* __restrict__ loss_accum,
                                float* __restrict__ out_losses) {
    float m = loss_accum[0] * (1.0f / (float)ZST_ELEMS);
    out_losses[0] = m;
    out_losses[1] = m;
}

// ---------------- launch ----------------
extern "C" void kernel_launch(void* const* d_in, const int* in_sizes, int n_in,
                              void* d_out, int out_size, void* d_ws, size_t ws_size,
                              hipStream_t stream) {
    const float* z   = (const float*)d_in[0];   // [8,4096,256]
    const float* emb = (const float*)d_in[1];   // [8192,256]

    float* out    = (float*)d_out;
    float* zst    = out;                        // 8388608
    float* idxf   = out + ZST_ELEMS;            // 32768
    float* losses = out + ZST_ELEMS + N_TOK;    // 2

    char* w = (char*)d_ws;
    unsigned short* Ah = (unsigned short*)w;    w += (size_t)N_TOK  * HIDDEN * 2;
    unsigned short* Al = (unsigned short*)w;    w += (size_t)N_TOK  * HIDDEN * 2;
    unsigned short* Bh = (unsigned short*)w;    w += (size_t)K_CODES * HIDDEN * 2;
    float* p1 = (float*)w;                      w += (size_t)NBLK * N_TOK * 4;
    float* p2 = (float*)w;                      w += (size_t)NBLK * N_TOK * 4;
    unsigned short* piu = (unsigned short*)w;   w += (size_t)NBLK * N_TOK * 2;
    float* ne = (float*)w;                      w += K_CODES * 4;
    float* zn = (float*)w;                      w += N_TOK * 4;
    int*   flags = (int*)w;                     w += N_TOK * 4;
    unsigned long long* slots = (unsigned long long*)w;  w += N_TOK * 8;
    int*   wl = (int*)w;                        w += (size_t)WL_CAP * 4;
    float* loss_accum = (float*)w;              w += 4;
    unsigned int* wcount = (unsigned int*)w;    // adjacent to loss_accum

    hipMemsetAsync(loss_accum, 0, 8, stream);   // zero loss + worklist counter
    np_norms_kernel<<<K_CODES * 16 / 256, 256, 0, stream>>>(emb, ne, K_CODES);
    np_norms_kernel<<<N_TOK * 16 / 256, 256, 0, stream>>>(z, zn, N_TOK);
    split_kernel<<<(ZST_ELEMS / 4) / 256, 256, 0, stream>>>(z, Ah, Al, ZST_ELEMS / 4);
    split_hi_kernel<<<(K_CODES * HIDDEN / 4) / 256, 256, 0, stream>>>(emb, Bh,
                                                                      K_CODES * HIDDEN / 4);
    dim3 gg(N_TOK / 128, NBLK);
    mfma_score_kernel<<<gg, 256, 0, stream>>>(Ah, Al, Bh, ne, p1, p2, piu);
    combine_kernel<<<N_TOK / 256, 256, 0, stream>>>(p1, p2, piu, idxf, flags,
                                                    slots, wl, wcount);
    rescue_scan<<<2048, 64, 0, stream>>>(z, emb, ne, zn, wl, wcount, slots);
    epilogue_kernel<<<(ZST_ELEMS / 4) / 256, 256, 0, stream>>>(z, emb, flags, slots,
                                                               idxf, zst, loss_accum);
    finalize_kernel<<<1, 1, 0, stream>>>(loss_accum, losses);
}